// Round 17
// baseline (138.986 us; speedup 1.0000x reference)
//
#include <hip/hip_runtime.h>
#include <hip/hip_bf16.h>
#include <cstdint>
#include <cstddef>

#define NB 2
#define NS 2048
#define ND 1024
#define NH 16
#define NDK 64
#define NT (NS / 64)

typedef __attribute__((ext_vector_type(4))) float f32x4;
typedef __attribute__((ext_vector_type(8))) short bf16x8;

#define MFMA_16x16x32_BF16(a,b,c) __builtin_amdgcn_mfma_f32_16x16x32_bf16((a),(b),(c),0,0,0)

__device__ __forceinline__ uint16_t f2bf(float f){
  uint32_t u = __float_as_uint(f);
  u += 0x7fffu + ((u >> 16) & 1u);   // round-to-nearest-even
  return (uint16_t)(u >> 16);
}
__device__ __forceinline__ uint32_t bfpack2(float a, float b){
  uint32_t r;
  asm volatile("v_cvt_pk_bf16_f32 %0, %1, %2" : "=v"(r) : "v"(a), "v"(b));
  return r;
}
// raw HW exp2 (safe: inputs bounded, no denormal path needed; masked after)
__device__ __forceinline__ float fexp2(float x){
  float r;
  asm volatile("v_exp_f32 %0, %1" : "=v"(r) : "v"(x));
  return r;
}
__device__ __forceinline__ void gload_lds16(const void* g, void* l){
  __builtin_amdgcn_global_load_lds((const __attribute__((address_space(1))) void*)g,
                                   (__attribute__((address_space(3))) void*)l, 16, 0, 0);
}

// ------- fused prep: y=0..2 act cvt, y=3 mask->bits, y=4..7 weight cvt ------
__global__ void prep_all(const float* __restrict__ q, const float* __restrict__ k,
                         const float* __restrict__ v,
                         const float* __restrict__ wq, const float* __restrict__ wk,
                         const float* __restrict__ wv, const float* __restrict__ wo,
                         uint16_t* __restrict__ oq, uint16_t* __restrict__ ok,
                         uint16_t* __restrict__ ov,
                         uint16_t* __restrict__ owq, uint16_t* __restrict__ owk,
                         uint16_t* __restrict__ owv, uint16_t* __restrict__ owo,
                         const int* __restrict__ mask, unsigned long long* __restrict__ bits,
                         int n8a, int n8w, int nchunks){
  const int y = blockIdx.y;
  if(y == 3){
    int wid  = (blockIdx.x * blockDim.x + threadIdx.x) >> 6;
    int lane = threadIdx.x & 63;
    int nw   = (gridDim.x * blockDim.x) >> 6;
    for(int ch = wid; ch < nchunks; ch += nw){
      int mv = mask[(size_t)ch * 64 + lane];
      unsigned long long bb = __ballot(mv != 0);
      if(lane == 0) bits[ch] = bb;
    }
    return;
  }
  const float* in; uint16_t* out; int n8;
  switch(y){
    case 0: in = q;  out = oq;  n8 = n8a; break;
    case 1: in = k;  out = ok;  n8 = n8a; break;
    case 2: in = v;  out = ov;  n8 = n8a; break;
    case 4: in = wq; out = owq; n8 = n8w; break;
    case 5: in = wk; out = owk; n8 = n8w; break;
    case 6: in = wv; out = owv; n8 = n8w; break;
    default: in = wo; out = owo; n8 = n8w; break;
  }
  int i0 = blockIdx.x * blockDim.x + threadIdx.x;
  int stride = gridDim.x * blockDim.x;
  for(int i = i0; i < n8; i += stride){
    const float4* p = (const float4*)(in) + (size_t)i * 2;
    float4 x = p[0], yv = p[1];
    bf16x8 o;
    o[0]=(short)f2bf(x.x);  o[1]=(short)f2bf(x.y);  o[2]=(short)f2bf(x.z);  o[3]=(short)f2bf(x.w);
    o[4]=(short)f2bf(yv.x); o[5]=(short)f2bf(yv.y); o[6]=(short)f2bf(yv.z); o[7]=(short)f2bf(yv.w);
    *((bf16x8*)(out) + i) = o;
  }
}

// ---------------- GEMM: 512 threads / 8 waves, 128x128 tile -----------------
// 2 K-tiles (BK=128 effective) per barrier pair: stage 8 gloads -> sync ->
// 32 MFMA/wave -> sync. LDS 64KB; at 8-wave blocks occupancy stays 2 blocks/CU.
// Wave w owns 64x32 sub-tile: wr=(w>>2)*64, wc=(w&3)*32, acc[4][2].
// qscale: epilogue scale for z==0 (folds softmax log2e/sqrt(dk) into Q).
// vtz: if z == vtz, write output transposed per-head: Vt[(b,h),dk,s] (bf16).
template<bool OUTF32>
__global__ __launch_bounds__(512, 4)
void gemm_bt(const uint16_t* __restrict__ A0, const uint16_t* __restrict__ A1, const uint16_t* __restrict__ A2,
             const uint16_t* __restrict__ W0, const uint16_t* __restrict__ W1, const uint16_t* __restrict__ W2,
             const float* __restrict__ b0, const float* __restrict__ b1, const float* __restrict__ b2,
             void* __restrict__ C0, void* __restrict__ C1, void* __restrict__ C2,
             int M, int N, int K, int vtz, float qscale)
{
  const int z = blockIdx.z;
  const uint16_t* A   = (z == 0) ? A0 : (z == 1) ? A1 : A2;
  const uint16_t* W   = (z == 0) ? W0 : (z == 1) ? W1 : W2;
  const float*   bias = (z == 0) ? b0 : (z == 1) ? b1 : b2;
  void*          Cout = (z == 0) ? C0 : (z == 1) ? C1 : C2;
  const float    csc  = (z == 0) ? qscale : 1.0f;

  __shared__ __align__(16) uint16_t Asm[2][128 * 64];
  __shared__ __align__(16) uint16_t Bsm[2][128 * 64];

  const int t = threadIdx.x;
  const int lane = t & 63, w = t >> 6;          // w = 0..7
  const int l15 = lane & 15, g = lane >> 4;
  const int bm = blockIdx.y * 128, bn = blockIdx.x * 128;
  const int wr = (w >> 2) * 64, wc = (w & 3) * 32;

  f32x4 acc[4][2] = {};

  const int srow = lane >> 3;
  const int schk = (lane & 7) ^ srow;

  const uint16_t* gA = A + (size_t)(bm + w * 16 + srow) * K + schk * 8;
  const uint16_t* gB = W + (size_t)(bn + w * 16 + srow) * K + schk * 8;
  uint16_t* lA = &Asm[0][(w * 16) * 64];
  uint16_t* lB = &Bsm[0][(w * 16) * 64];

  const int xr = l15 & 7;
  int aOff[2][4], bOff[2][2];
  #pragma unroll
  for(int kk = 0; kk < 2; ++kk){
    #pragma unroll
    for(int m = 0; m < 4; ++m)
      aOff[kk][m] = (wr + m*16 + l15) * 64 + (((kk*4 + g) ^ xr) << 3);
    #pragma unroll
    for(int n = 0; n < 2; ++n)
      bOff[kk][n] = (wc + n*16 + l15) * 64 + (((kk*4 + g) ^ xr) << 3);
  }

  for(int k0 = 0; k0 < K; k0 += 128){
    #pragma unroll
    for(int hlf = 0; hlf < 2; ++hlf){
      #pragma unroll
      for(int j = 0; j < 2; ++j){
        gload_lds16(gA + (size_t)(8 * j) * K, lA + hlf * 8192 + (8 * j) * 64);
        gload_lds16(gB + (size_t)(8 * j) * K, lB + hlf * 8192 + (8 * j) * 64);
      }
      gA += 64; gB += 64;
    }
    __syncthreads();
    #pragma unroll
    for(int hlf = 0; hlf < 2; ++hlf){
      const uint16_t* As = &Asm[hlf][0];
      const uint16_t* Bs = &Bsm[hlf][0];
      #pragma unroll
      for(int kk = 0; kk < 2; ++kk){
        bf16x8 af[4], bfr[2];
        #pragma unroll
        for(int m = 0; m < 4; ++m) af[m]  = *(const bf16x8*)&As[aOff[kk][m]];
        #pragma unroll
        for(int n = 0; n < 2; ++n) bfr[n] = *(const bf16x8*)&Bs[bOff[kk][n]];
        #pragma unroll
        for(int m = 0; m < 4; ++m)
          #pragma unroll
          for(int n = 0; n < 2; ++n)
            acc[m][n] = MFMA_16x16x32_BF16(af[m], bfr[n], acc[m][n]);
      }
    }
    __syncthreads();
  }

  if(z == vtz){
    uint16_t* Vt = (uint16_t*)Cout;
    #pragma unroll
    for(int m = 0; m < 4; ++m){
      const int row = bm + wr + m*16 + g*4;
      const int bb = row >> 11, ss = row & (NS - 1);
      #pragma unroll
      for(int n = 0; n < 2; ++n){
        const int col = bn + wc + n*16 + l15;
        const float bv = bias[col];
        float v0 = acc[m][n][0] + bv, v1 = acc[m][n][1] + bv;
        float v2 = acc[m][n][2] + bv, v3 = acc[m][n][3] + bv;
        uint2 pk; pk.x = bfpack2(v0, v1); pk.y = bfpack2(v2, v3);
        size_t dst = ((size_t)(bb * NH + (col >> 6)) * NDK + (col & 63)) * NS + ss;
        *(uint2*)&Vt[dst] = pk;
      }
    }
  } else {
    #pragma unroll
    for(int m = 0; m < 4; ++m){
      const int row = bm + wr + m*16 + g*4;
      #pragma unroll
      for(int n = 0; n < 2; ++n){
        const int col = bn + wc + n*16 + l15;
        const float bv = bias[col];
        #pragma unroll
        for(int j = 0; j < 4; ++j){
          float v = (acc[m][n][j] + bv) * csc;
          if (OUTF32) ((float*)Cout)[(size_t)(row + j) * N + col] = v;
          else        ((uint16_t*)Cout)[(size_t)(row + j) * N + col] = f2bf(v);
        }
      }
    }
  }
}

// ---------------- Flash attention: QBLK=128, 8 waves, 2 kv-tiles/barrier ----
// 4-buffer LDS (2 pairs). Pair staging = 4 gload_lds + 1 uint4 mask load
// (= 5 vmem): vmcnt(5) -> barrier -> compute both tiles -> lgkmcnt(0) ->
// barrier. Raw exp2, bfe mask, ones-MFMA denominator, Q pre-scaled.
__device__ __forceinline__ int swz64(int r, int chunk){
  return r * 64 + (((chunk) ^ (r & 7)) << 3);
}

__global__ __launch_bounds__(512, 2)
void attn_fwd(const uint16_t* __restrict__ Qp, const uint16_t* __restrict__ Kp,
              const uint16_t* __restrict__ Vtg, const uint2* __restrict__ Mbits,
              uint16_t* __restrict__ Xo)
{
  __shared__ __align__(16) uint16_t Ksm[4][64 * 64];
  __shared__ __align__(16) uint16_t Vtsm[4][64 * 64];
  __shared__ __align__(16) uint16_t Psm[8][16 * 64];

  const int t = threadIdx.x, lane = t & 63, w = t >> 6;   // w = 0..7
  const int l15 = lane & 15, g = lane >> 4;
  const int b = blockIdx.z, h = blockIdx.y, q0 = blockIdx.x * 128;
  const int qbase = q0 + w * 16;

  bf16x8 qf0, qf1;
  {
    const uint16_t* qptr = Qp + (size_t)(b * NS + qbase + l15) * ND + h * NDK + g * 8;
    qf0 = *(const bf16x8*)(qptr);
    qf1 = *(const bf16x8*)(qptr + 32);
  }

  bf16x8 ones;
  #pragma unroll
  for(int e = 0; e < 8; ++e) ones[e] = (short)0x3F80;   // bf16 1.0

  f32x4 acc[4] = {};
  f32x4 acl = {};

  // staging: wave w stages 8 rows (w*8..w*8+7) of K and of Vt per tile
  const int srow = lane >> 3;              // 0..7
  const int schk = (lane & 7) ^ srow;      // XOR involution within 8-row group

  const uint16_t* gK0 = Kp + (size_t)(b * NS + w * 8 + srow) * ND + h * NDK + schk * 8;
  const uint16_t* gV0 = Vtg + (size_t)(b * NH + h) * NDK * NS + (size_t)(w * 8 + srow) * NS + schk * 8;

  uint16_t* lK = &Ksm[0][(w * 8) * 64];
  uint16_t* lV = &Vtsm[0][(w * 8) * 64];

  int kOffA[4], kOffB[4], vOff[2][4];
  #pragma unroll
  for(int i = 0; i < 4; ++i){
    kOffA[i] = swz64(i * 16 + l15, g);
    kOffB[i] = swz64(i * 16 + l15, g + 4);
  }
  #pragma unroll
  for(int c2 = 0; c2 < 2; ++c2)
    #pragma unroll
    for(int tt = 0; tt < 4; ++tt)
      vOff[c2][tt] = swz64(tt * 16 + l15, c2 * 4 + g);
  const int xorw = (l15 & 7) << 3;
  const int prow = l15 * 64;
  int pW[4], pR[2];
  #pragma unroll
  for(int i = 0; i < 4; ++i) pW[i] = prow + ((16 * i + g * 4) ^ xorw);
  #pragma unroll
  for(int c2 = 0; c2 < 2; ++c2) pR[c2] = prow + ((c2 * 32 + g * 8) ^ xorw);
  uint16_t* PsmW = Psm[w];

  // mask: one uint4 per pair (bits for 128 kv)
  const uint4* Mptr4 = (const uint4*)(Mbits + (size_t)(b * NS + qbase + l15) * (NS / 64) / 1);

  // prologue: stage tiles 0,1 into pair 0 (4 gloads + 1 uint4 = 5 vmem)
  gload_lds16(gK0,           lK);
  gload_lds16(gV0,           lV);
  gload_lds16(gK0 + 64 * ND, lK + 4096);
  gload_lds16(gV0 + 64,      lV + 4096);
  uint4 mmp = Mptr4[0];
  gK0 += 128 * ND; gV0 += 128;

  int p = 0;
  for(int it = 0; it < NT / 2; ++it){
    uint4 mnp;
    if(it + 1 < NT / 2){
      const int nc = (p ^ 1) * 8192;
      gload_lds16(gK0,           lK + nc);
      gload_lds16(gV0,           lV + nc);
      gload_lds16(gK0 + 64 * ND, lK + nc + 4096);
      gload_lds16(gV0 + 64,      lV + nc + 4096);
      mnp = Mptr4[it + 1];
      gK0 += 128 * ND; gV0 += 128;
      asm volatile("s_waitcnt vmcnt(5)" ::: "memory");   // this pair's 5 landed
    } else {
      asm volatile("s_waitcnt vmcnt(0)" ::: "memory");
    }
    __builtin_amdgcn_s_barrier();

    #pragma unroll
    for(int half = 0; half < 2; ++half){
      const uint16_t* Kc = &Ksm[0][p * 8192 + half * 4096];
      const uint16_t* Vc = &Vtsm[0][p * 8192 + half * 4096];
      const uint32_t mx = half ? mmp.z : mmp.x;
      const uint32_t my = half ? mmp.w : mmp.y;

      // QK^T swapped: s4[i] row=kv(16i+g*4+j), col=q(l15); Q pre-scaled
      f32x4 s4[4];
      __builtin_amdgcn_s_setprio(1);
      #pragma unroll
      for(int i = 0; i < 4; ++i){
        bf16x8 kf0 = *(const bf16x8*)&Kc[kOffA[i]];
        bf16x8 kf1 = *(const bf16x8*)&Kc[kOffB[i]];
        f32x4 zr = {};
        zr = MFMA_16x16x32_BF16(kf0, qf0, zr);
        zr = MFMA_16x16x32_BF16(kf1, qf1, zr);
        s4[i] = zr;
      }
      __builtin_amdgcn_s_setprio(0);

      // p = exp2(s) [raw v_exp_f32]; mask via 1-op v_bfe_i32 bit sign-extend
      const uint32_t w0 = mx >> (g * 4);
      const uint32_t w1 = my >> (g * 4);
      #pragma unroll
      for(int i = 0; i < 4; ++i){
        const uint32_t ww = (i < 2) ? w0 : w1;
        float e0 = fexp2(s4[i][0]);
        float e1 = fexp2(s4[i][1]);
        float e2 = fexp2(s4[i][2]);
        float e3 = fexp2(s4[i][3]);
        int m0, m1, m2, m3;
        if((i & 1) == 0){
          asm("v_bfe_i32 %0, %1, 0, 1" : "=v"(m0) : "v"(ww));
          asm("v_bfe_i32 %0, %1, 1, 1" : "=v"(m1) : "v"(ww));
          asm("v_bfe_i32 %0, %1, 2, 1" : "=v"(m2) : "v"(ww));
          asm("v_bfe_i32 %0, %1, 3, 1" : "=v"(m3) : "v"(ww));
        } else {
          asm("v_bfe_i32 %0, %1, 16, 1" : "=v"(m0) : "v"(ww));
          asm("v_bfe_i32 %0, %1, 17, 1" : "=v"(m1) : "v"(ww));
          asm("v_bfe_i32 %0, %1, 18, 1" : "=v"(m2) : "v"(ww));
          asm("v_bfe_i32 %0, %1, 19, 1" : "=v"(m3) : "v"(ww));
        }
        s4[i][0] = __uint_as_float((uint32_t)m0 & __float_as_uint(e0));
        s4[i][1] = __uint_as_float((uint32_t)m1 & __float_as_uint(e1));
        s4[i][2] = __uint_as_float((uint32_t)m2 & __float_as_uint(e2));
        s4[i][3] = __uint_as_float((uint32_t)m3 & __float_as_uint(e3));
      }

      // pack P -> per-wave LDS (b64 writes)
      #pragma unroll
      for(int i = 0; i < 4; ++i){
        uint2 pk;
        pk.x = bfpack2(s4[i][0], s4[i][1]);
        pk.y = bfpack2(s4[i][2], s4[i][3]);
        *(uint2*)&PsmW[pW[i]] = pk;
      }

      // PV (+ denominator via ones-column MFMA)
      __builtin_amdgcn_s_setprio(1);
      #pragma unroll
      for(int c2 = 0; c2 < 2; ++c2){
        bf16x8 pf = *(const bf16x8*)&PsmW[pR[c2]];
        acl = MFMA_16x16x32_BF16(pf, ones, acl);
        #pragma unroll
        for(int tt = 0; tt < 4; ++tt){
          bf16x8 vf = *(const bf16x8*)&Vc[vOff[c2][tt]];
          acc[tt] = MFMA_16x16x32_BF16(pf, vf, acc[tt]);
        }
      }
      __builtin_amdgcn_s_setprio(0);
    }

    asm volatile("s_waitcnt lgkmcnt(0)" ::: "memory");
    __builtin_amdgcn_s_barrier();
    p ^= 1;
    mmp = mnp;
  }

  // finalize: l already in output-row layout (row = g*4+j)
  #pragma unroll
  for(int j = 0; j < 4; ++j){
    const float inv = 1.0f / acl[j];
    const int qr = qbase + g * 4 + j;
    #pragma unroll
    for(int tt = 0; tt < 4; ++tt)
      Xo[(size_t)(b * NS + qr) * ND + h * NDK + tt * 16 + l15] = f2bf(acc[tt][j] * inv);
  }
}

// ---------------- host launch ------------------------------------------------
extern "C" void kernel_launch(void* const* d_in, const int* in_sizes, int n_in,
                              void* d_out, int out_size, void* d_ws, size_t ws_size,
                              hipStream_t stream)
{
  const float* query = (const float*)d_in[0];
  const float* key   = (const float*)d_in[1];
  const float* value = (const float*)d_in[2];
  const int*   mask  = (const int*)d_in[3];
  const float* Wq = (const float*)d_in[4];
  const float* bq = (const float*)d_in[5];
  const float* Wk = (const float*)d_in[6];
  const float* bk = (const float*)d_in[7];
  const float* Wv = (const float*)d_in[8];
  const float* bv = (const float*)d_in[9];
  const float* Wo = (const float*)d_in[10];
  const float* bo = (const float*)d_in[11];
  float* out = (float*)d_out;

  const size_t NX = (size_t)NB * NS * ND;   // 4,194,304
  const size_t NW = (size_t)ND * ND;        // 1,048,576

  uint16_t* ws  = (uint16_t*)d_ws;
  uint16_t* Xq  = ws;            // bf16 activations
  uint16_t* Xk  = Xq  + NX;
  uint16_t* Xv  = Xk  + NX;
  uint16_t* Wqb = Xv  + NX;
  uint16_t* Wkb = Wqb + NW;
  uint16_t* Wvb = Wkb + NW;
  uint16_t* Wob = Wvb + NW;
  uint16_t* Qp  = Wob + NW;
  uint16_t* Kp  = Qp  + NX;
  uint16_t* Vt  = Kp  + NX;      // V^T written directly by proj epilogue (z==2)
  uint16_t* Xa  = Vt  + NX;
  unsigned long long* Mb = (unsigned long long*)(Xa + NX);   // 1MB, own slot

  const int nchunks = (int)((size_t)NB * NS * NS / 64);   // 131072
  const float QSCL = 0.125f * 1.44269504f;   // log2(e)/sqrt(DK)

  prep_all<<<dim3(1024, 8), 256, 0, stream>>>(query, key, value, Wq, Wk, Wv, Wo,
                                              Xq, Xk, Xv, Wqb, Wkb, Wvb, Wob,
                                              mask, Mb, (int)(NX / 8), (int)(NW / 8), nchunks);

  dim3 gproj(ND / 128, (NB * NS) / 128, 3);
  gemm_bt<false><<<gproj, 512, 0, stream>>>(Xq, Xk, Xv,
                                            Wqb, Wkb, Wvb,
                                            bq, bk, bv,
                                            (void*)Qp, (void*)Kp, (void*)Vt,
                                            NB * NS, ND, ND, 2, QSCL);

  attn_fwd<<<dim3(NS / 128, NH, NB), 512, 0, stream>>>(Qp, Kp, Vt, (const uint2*)Mb, Xa);

  dim3 gout(ND / 128, (NB * NS) / 128, 1);
  gemm_bt<true><<<gout, 512, 0, stream>>>(Xa, Xa, Xa,
                                          Wob, Wob, Wob,
                                          bo, bo, bo,
                                          (void*)out, (void*)out, (void*)out,
                                          NB * NS, ND, ND, -1, 1.0f);
}

// Round 18
// 135.334 us; speedup vs baseline: 1.0270x; 1.0270x over previous
//
#include <hip/hip_runtime.h>
#include <hip/hip_bf16.h>
#include <cstdint>
#include <cstddef>

#define NB 2
#define NS 2048
#define ND 1024
#define NH 16
#define NDK 64
#define NT (NS / 64)

typedef __attribute__((ext_vector_type(4))) float f32x4;
typedef __attribute__((ext_vector_type(8))) short bf16x8;

#define MFMA_16x16x32_BF16(a,b,c) __builtin_amdgcn_mfma_f32_16x16x32_bf16((a),(b),(c),0,0,0)

__device__ __forceinline__ uint16_t f2bf(float f){
  uint32_t u = __float_as_uint(f);
  u += 0x7fffu + ((u >> 16) & 1u);   // round-to-nearest-even
  return (uint16_t)(u >> 16);
}
__device__ __forceinline__ uint32_t bfpack2(float a, float b){
  uint32_t r;
  asm volatile("v_cvt_pk_bf16_f32 %0, %1, %2" : "=v"(r) : "v"(a), "v"(b));
  return r;
}
// raw HW exp2 (safe: inputs bounded, no denormal path needed; masked after)
__device__ __forceinline__ float fexp2(float x){
  float r;
  asm volatile("v_exp_f32 %0, %1" : "=v"(r) : "v"(x));
  return r;
}
__device__ __forceinline__ void gload_lds16(const void* g, void* l){
  __builtin_amdgcn_global_load_lds((const __attribute__((address_space(1))) void*)g,
                                   (__attribute__((address_space(3))) void*)l, 16, 0, 0);
}

// ------- fused prep: y=0..2 act cvt, y=3 mask->bits, y=4..7 weight cvt ------
__global__ void prep_all(const float* __restrict__ q, const float* __restrict__ k,
                         const float* __restrict__ v,
                         const float* __restrict__ wq, const float* __restrict__ wk,
                         const float* __restrict__ wv, const float* __restrict__ wo,
                         uint16_t* __restrict__ oq, uint16_t* __restrict__ ok,
                         uint16_t* __restrict__ ov,
                         uint16_t* __restrict__ owq, uint16_t* __restrict__ owk,
                         uint16_t* __restrict__ owv, uint16_t* __restrict__ owo,
                         const int* __restrict__ mask, unsigned long long* __restrict__ bits,
                         int n8a, int n8w, int nchunks){
  const int y = blockIdx.y;
  if(y == 3){
    int wid  = (blockIdx.x * blockDim.x + threadIdx.x) >> 6;
    int lane = threadIdx.x & 63;
    int nw   = (gridDim.x * blockDim.x) >> 6;
    for(int ch = wid; ch < nchunks; ch += nw){
      int mv = mask[(size_t)ch * 64 + lane];
      unsigned long long bb = __ballot(mv != 0);
      if(lane == 0) bits[ch] = bb;
    }
    return;
  }
  const float* in; uint16_t* out; int n8;
  switch(y){
    case 0: in = q;  out = oq;  n8 = n8a; break;
    case 1: in = k;  out = ok;  n8 = n8a; break;
    case 2: in = v;  out = ov;  n8 = n8a; break;
    case 4: in = wq; out = owq; n8 = n8w; break;
    case 5: in = wk; out = owk; n8 = n8w; break;
    case 6: in = wv; out = owv; n8 = n8w; break;
    default: in = wo; out = owo; n8 = n8w; break;
  }
  int i0 = blockIdx.x * blockDim.x + threadIdx.x;
  int stride = gridDim.x * blockDim.x;
  for(int i = i0; i < n8; i += stride){
    const float4* p = (const float4*)(in) + (size_t)i * 2;
    float4 x = p[0], yv = p[1];
    bf16x8 o;
    o[0]=(short)f2bf(x.x);  o[1]=(short)f2bf(x.y);  o[2]=(short)f2bf(x.z);  o[3]=(short)f2bf(x.w);
    o[4]=(short)f2bf(yv.x); o[5]=(short)f2bf(yv.y); o[6]=(short)f2bf(yv.z); o[7]=(short)f2bf(yv.w);
    *((bf16x8*)(out) + i) = o;
  }
}

// ---------------- GEMM: 512 threads / 8 waves, 128x128 tile, BK=64 ----------
// (R16 known-good single-buffer form.) Wave w owns 64x32 sub-tile.
// qscale: epilogue scale for z==0; vtz: transposed per-head Vt output for z==vtz.
template<bool OUTF32>
__global__ __launch_bounds__(512, 4)
void gemm_bt(const uint16_t* __restrict__ A0, const uint16_t* __restrict__ A1, const uint16_t* __restrict__ A2,
             const uint16_t* __restrict__ W0, const uint16_t* __restrict__ W1, const uint16_t* __restrict__ W2,
             const float* __restrict__ b0, const float* __restrict__ b1, const float* __restrict__ b2,
             void* __restrict__ C0, void* __restrict__ C1, void* __restrict__ C2,
             int M, int N, int K, int vtz, float qscale)
{
  const int z = blockIdx.z;
  const uint16_t* A   = (z == 0) ? A0 : (z == 1) ? A1 : A2;
  const uint16_t* W   = (z == 0) ? W0 : (z == 1) ? W1 : W2;
  const float*   bias = (z == 0) ? b0 : (z == 1) ? b1 : b2;
  void*          Cout = (z == 0) ? C0 : (z == 1) ? C1 : C2;
  const float    csc  = (z == 0) ? qscale : 1.0f;

  __shared__ __align__(16) uint16_t Asm[128 * 64];
  __shared__ __align__(16) uint16_t Bsm[128 * 64];

  const int t = threadIdx.x;
  const int lane = t & 63, w = t >> 6;          // w = 0..7
  const int l15 = lane & 15, g = lane >> 4;
  const int bm = blockIdx.y * 128, bn = blockIdx.x * 128;
  const int wr = (w >> 2) * 64, wc = (w & 3) * 32;

  f32x4 acc[4][2] = {};

  const int srow = lane >> 3;
  const int schk = (lane & 7) ^ srow;

  const uint16_t* gA = A + (size_t)(bm + w * 16 + srow) * K + schk * 8;
  const uint16_t* gB = W + (size_t)(bn + w * 16 + srow) * K + schk * 8;
  uint16_t* lA = &Asm[(w * 16) * 64];
  uint16_t* lB = &Bsm[(w * 16) * 64];

  const int xr = l15 & 7;
  int aOff[2][4], bOff[2][2];
  #pragma unroll
  for(int kk = 0; kk < 2; ++kk){
    #pragma unroll
    for(int m = 0; m < 4; ++m)
      aOff[kk][m] = (wr + m*16 + l15) * 64 + (((kk*4 + g) ^ xr) << 3);
    #pragma unroll
    for(int n = 0; n < 2; ++n)
      bOff[kk][n] = (wc + n*16 + l15) * 64 + (((kk*4 + g) ^ xr) << 3);
  }

  for(int k0 = 0; k0 < K; k0 += 64){
    #pragma unroll
    for(int j = 0; j < 2; ++j){
      gload_lds16(gA + (size_t)(8 * j) * K, lA + (8 * j) * 64);
      gload_lds16(gB + (size_t)(8 * j) * K, lB + (8 * j) * 64);
    }
    gA += 64; gB += 64;
    __syncthreads();
    #pragma unroll
    for(int kk = 0; kk < 2; ++kk){
      bf16x8 af[4], bfr[2];
      #pragma unroll
      for(int m = 0; m < 4; ++m) af[m]  = *(const bf16x8*)&Asm[aOff[kk][m]];
      #pragma unroll
      for(int n = 0; n < 2; ++n) bfr[n] = *(const bf16x8*)&Bsm[bOff[kk][n]];
      #pragma unroll
      for(int m = 0; m < 4; ++m)
        #pragma unroll
        for(int n = 0; n < 2; ++n)
          acc[m][n] = MFMA_16x16x32_BF16(af[m], bfr[n], acc[m][n]);
    }
    __syncthreads();
  }

  if(z == vtz){
    uint16_t* Vt = (uint16_t*)Cout;
    #pragma unroll
    for(int m = 0; m < 4; ++m){
      const int row = bm + wr + m*16 + g*4;
      const int bb = row >> 11, ss = row & (NS - 1);
      #pragma unroll
      for(int n = 0; n < 2; ++n){
        const int col = bn + wc + n*16 + l15;
        const float bv = bias[col];
        float v0 = acc[m][n][0] + bv, v1 = acc[m][n][1] + bv;
        float v2 = acc[m][n][2] + bv, v3 = acc[m][n][3] + bv;
        uint2 pk; pk.x = bfpack2(v0, v1); pk.y = bfpack2(v2, v3);
        size_t dst = ((size_t)(bb * NH + (col >> 6)) * NDK + (col & 63)) * NS + ss;
        *(uint2*)&Vt[dst] = pk;
      }
    }
  } else {
    #pragma unroll
    for(int m = 0; m < 4; ++m){
      const int row = bm + wr + m*16 + g*4;
      #pragma unroll
      for(int n = 0; n < 2; ++n){
        const int col = bn + wc + n*16 + l15;
        const float bv = bias[col];
        #pragma unroll
        for(int j = 0; j < 4; ++j){
          float v = (acc[m][n][j] + bv) * csc;
          if (OUTF32) ((float*)Cout)[(size_t)(row + j) * N + col] = v;
          else        ((uint16_t*)Cout)[(size_t)(row + j) * N + col] = f2bf(v);
        }
      }
    }
  }
}

// ---------------- Flash attention: QBLK=128, 8 waves, 2 kv-tiles/barrier ----
// XCD-aware 1-D grid (512 blocks): xcd = lin&7 owns head-batches 4*xcd..+3,
// so each XCD's L2 holds only 4 heads' K/V (2MB, fits 4MB L2) instead of all.
// 4-buffer LDS (2 pairs), 6 vmem/pair, vmcnt(6) counted wait, raw exp2,
// bfe mask, ones-MFMA denominator, Q pre-scaled.
__device__ __forceinline__ int swz64(int r, int chunk){
  return r * 64 + (((chunk) ^ (r & 7)) << 3);
}

__global__ __launch_bounds__(512, 2)
void attn_fwd(const uint16_t* __restrict__ Qp, const uint16_t* __restrict__ Kp,
              const uint16_t* __restrict__ Vtg, const uint2* __restrict__ Mbits,
              uint16_t* __restrict__ Xo)
{
  __shared__ __align__(16) uint16_t Ksm[4][64 * 64];
  __shared__ __align__(16) uint16_t Vtsm[4][64 * 64];
  __shared__ __align__(16) uint16_t Psm[8][16 * 64];

  // XCD-aware decomposition of the 1-D grid (HW assigns block i -> XCD i%8)
  const int lin = blockIdx.x;
  const int xcd = lin & 7, idx = lin >> 3;
  const int hb  = xcd * 4 + (idx >> 4);       // head-batch 0..31
  const int b   = hb >> 4, h = hb & 15;
  const int q0  = (idx & 15) * 128;

  const int t = threadIdx.x, lane = t & 63, w = t >> 6;   // w = 0..7
  const int l15 = lane & 15, g = lane >> 4;
  const int qbase = q0 + w * 16;

  bf16x8 qf0, qf1;
  {
    const uint16_t* qptr = Qp + (size_t)(b * NS + qbase + l15) * ND + h * NDK + g * 8;
    qf0 = *(const bf16x8*)(qptr);
    qf1 = *(const bf16x8*)(qptr + 32);
  }

  bf16x8 ones;
  #pragma unroll
  for(int e = 0; e < 8; ++e) ones[e] = (short)0x3F80;   // bf16 1.0

  f32x4 acc[4] = {};
  f32x4 acl = {};

  const int srow = lane >> 3;              // 0..7
  const int schk = (lane & 7) ^ srow;      // XOR involution within 8-row group

  const uint16_t* gK0 = Kp + (size_t)(b * NS + w * 8 + srow) * ND + h * NDK + schk * 8;
  const uint16_t* gV0 = Vtg + (size_t)(b * NH + h) * NDK * NS + (size_t)(w * 8 + srow) * NS + schk * 8;

  uint16_t* lK = &Ksm[0][(w * 8) * 64];
  uint16_t* lV = &Vtsm[0][(w * 8) * 64];

  int kOffA[4], kOffB[4], vOff[2][4];
  #pragma unroll
  for(int i = 0; i < 4; ++i){
    kOffA[i] = swz64(i * 16 + l15, g);
    kOffB[i] = swz64(i * 16 + l15, g + 4);
  }
  #pragma unroll
  for(int c2 = 0; c2 < 2; ++c2)
    #pragma unroll
    for(int tt = 0; tt < 4; ++tt)
      vOff[c2][tt] = swz64(tt * 16 + l15, c2 * 4 + g);
  const int xorw = (l15 & 7) << 3;
  const int prow = l15 * 64;
  int pW[4], pR[2];
  #pragma unroll
  for(int i = 0; i < 4; ++i) pW[i] = prow + ((16 * i + g * 4) ^ xorw);
  #pragma unroll
  for(int c2 = 0; c2 < 2; ++c2) pR[c2] = prow + ((c2 * 32 + g * 8) ^ xorw);
  uint16_t* PsmW = Psm[w];

  const uint2* Mptr = Mbits + (size_t)(b * NS + qbase + l15) * (NS / 64);

  // prologue: stage tiles 0,1 into pair 0 (4 gloads + 2 mask loads = 6 vmem)
  gload_lds16(gK0,           lK);
  gload_lds16(gV0,           lV);
  gload_lds16(gK0 + 64 * ND, lK + 4096);
  gload_lds16(gV0 + 64,      lV + 4096);
  uint2 mm0 = Mptr[0], mm1 = Mptr[1];
  gK0 += 128 * ND; gV0 += 128;

  int p = 0;
  for(int it = 0; it < NT / 2; ++it){
    uint2 mn0, mn1;
    if(it + 1 < NT / 2){
      const int nc = (p ^ 1) * 8192;
      gload_lds16(gK0,           lK + nc);
      gload_lds16(gV0,           lV + nc);
      gload_lds16(gK0 + 64 * ND, lK + nc + 4096);
      gload_lds16(gV0 + 64,      lV + nc + 4096);
      mn0 = Mptr[2 * it + 2];
      mn1 = Mptr[2 * it + 3];
      gK0 += 128 * ND; gV0 += 128;
      asm volatile("s_waitcnt vmcnt(6)" ::: "memory");   // this pair's 6 landed
    } else {
      asm volatile("s_waitcnt vmcnt(0)" ::: "memory");
    }
    __builtin_amdgcn_s_barrier();

    #pragma unroll
    for(int half = 0; half < 2; ++half){
      const uint16_t* Kc = &Ksm[0][p * 8192 + half * 4096];
      const uint16_t* Vc = &Vtsm[0][p * 8192 + half * 4096];
      const uint2 mm = half ? mm1 : mm0;

      // QK^T swapped: s4[i] row=kv(16i+g*4+j), col=q(l15); Q pre-scaled
      f32x4 s4[4];
      __builtin_amdgcn_s_setprio(1);
      #pragma unroll
      for(int i = 0; i < 4; ++i){
        bf16x8 kf0 = *(const bf16x8*)&Kc[kOffA[i]];
        bf16x8 kf1 = *(const bf16x8*)&Kc[kOffB[i]];
        f32x4 zr = {};
        zr = MFMA_16x16x32_BF16(kf0, qf0, zr);
        zr = MFMA_16x16x32_BF16(kf1, qf1, zr);
        s4[i] = zr;
      }
      __builtin_amdgcn_s_setprio(0);

      // p = exp2(s) [raw v_exp_f32]; mask via 1-op v_bfe_i32 bit sign-extend
      const uint32_t w0 = mm.x >> (g * 4);
      const uint32_t w1 = mm.y >> (g * 4);
      #pragma unroll
      for(int i = 0; i < 4; ++i){
        const uint32_t ww = (i < 2) ? w0 : w1;
        float e0 = fexp2(s4[i][0]);
        float e1 = fexp2(s4[i][1]);
        float e2 = fexp2(s4[i][2]);
        float e3 = fexp2(s4[i][3]);
        int m0, m1, m2, m3;
        if((i & 1) == 0){
          asm("v_bfe_i32 %0, %1, 0, 1" : "=v"(m0) : "v"(ww));
          asm("v_bfe_i32 %0, %1, 1, 1" : "=v"(m1) : "v"(ww));
          asm("v_bfe_i32 %0, %1, 2, 1" : "=v"(m2) : "v"(ww));
          asm("v_bfe_i32 %0, %1, 3, 1" : "=v"(m3) : "v"(ww));
        } else {
          asm("v_bfe_i32 %0, %1, 16, 1" : "=v"(m0) : "v"(ww));
          asm("v_bfe_i32 %0, %1, 17, 1" : "=v"(m1) : "v"(ww));
          asm("v_bfe_i32 %0, %1, 18, 1" : "=v"(m2) : "v"(ww));
          asm("v_bfe_i32 %0, %1, 19, 1" : "=v"(m3) : "v"(ww));
        }
        s4[i][0] = __uint_as_float((uint32_t)m0 & __float_as_uint(e0));
        s4[i][1] = __uint_as_float((uint32_t)m1 & __float_as_uint(e1));
        s4[i][2] = __uint_as_float((uint32_t)m2 & __float_as_uint(e2));
        s4[i][3] = __uint_as_float((uint32_t)m3 & __float_as_uint(e3));
      }

      // pack P -> per-wave LDS (b64 writes)
      #pragma unroll
      for(int i = 0; i < 4; ++i){
        uint2 pk;
        pk.x = bfpack2(s4[i][0], s4[i][1]);
        pk.y = bfpack2(s4[i][2], s4[i][3]);
        *(uint2*)&PsmW[pW[i]] = pk;
      }

      // PV (+ denominator via ones-column MFMA)
      __builtin_amdgcn_s_setprio(1);
      #pragma unroll
      for(int c2 = 0; c2 < 2; ++c2){
        bf16x8 pf = *(const bf16x8*)&PsmW[pR[c2]];
        acl = MFMA_16x16x32_BF16(pf, ones, acl);
        #pragma unroll
        for(int tt = 0; tt < 4; ++tt){
          bf16x8 vf = *(const bf16x8*)&Vc[vOff[c2][tt]];
          acc[tt] = MFMA_16x16x32_BF16(pf, vf, acc[tt]);
        }
      }
      __builtin_amdgcn_s_setprio(0);
    }

    asm volatile("s_waitcnt lgkmcnt(0)" ::: "memory");
    __builtin_amdgcn_s_barrier();
    p ^= 1;
    mm0 = mn0; mm1 = mn1;
  }

  // finalize: l already in output-row layout (row = g*4+j)
  #pragma unroll
  for(int j = 0; j < 4; ++j){
    const float inv = 1.0f / acl[j];
    const int qr = qbase + g * 4 + j;
    #pragma unroll
    for(int tt = 0; tt < 4; ++tt)
      Xo[(size_t)(b * NS + qr) * ND + h * NDK + tt * 16 + l15] = f2bf(acc[tt][j] * inv);
  }
}

// ---------------- host launch ------------------------------------------------
extern "C" void kernel_launch(void* const* d_in, const int* in_sizes, int n_in,
                              void* d_out, int out_size, void* d_ws, size_t ws_size,
                              hipStream_t stream)
{
  const float* query = (const float*)d_in[0];
  const float* key   = (const float*)d_in[1];
  const float* value = (const float*)d_in[2];
  const int*   mask  = (const int*)d_in[3];
  const float* Wq = (const float*)d_in[4];
  const float* bq = (const float*)d_in[5];
  const float* Wk = (const float*)d_in[6];
  const float* bk = (const float*)d_in[7];
  const float* Wv = (const float*)d_in[8];
  const float* bv = (const float*)d_in[9];
  const float* Wo = (const float*)d_in[10];
  const float* bo = (const float*)d_in[11];
  float* out = (float*)d_out;

  const size_t NX = (size_t)NB * NS * ND;   // 4,194,304
  const size_t NW = (size_t)ND * ND;        // 1,048,576

  uint16_t* ws  = (uint16_t*)d_ws;
  uint16_t* Xq  = ws;            // bf16 activations
  uint16_t* Xk  = Xq  + NX;
  uint16_t* Xv  = Xk  + NX;
  uint16_t* Wqb = Xv  + NX;
  uint16_t* Wkb = Wqb + NW;
  uint16_t* Wvb = Wkb + NW;
  uint16_t* Wob = Wvb + NW;
  uint16_t* Qp  = Wob + NW;
  uint16_t* Kp  = Qp  + NX;
  uint16_t* Vt  = Kp  + NX;      // V^T written directly by proj epilogue (z==2)
  uint16_t* Xa  = Vt  + NX;
  unsigned long long* Mb = (unsigned long long*)(Xa + NX);   // 1MB, own slot

  const int nchunks = (int)((size_t)NB * NS * NS / 64);   // 131072
  const float QSCL = 0.125f * 1.44269504f;   // log2(e)/sqrt(DK)

  prep_all<<<dim3(1024, 8), 256, 0, stream>>>(query, key, value, Wq, Wk, Wv, Wo,
                                              Xq, Xk, Xv, Wqb, Wkb, Wvb, Wob,
                                              mask, Mb, (int)(NX / 8), (int)(NW / 8), nchunks);

  dim3 gproj(ND / 128, (NB * NS) / 128, 3);
  gemm_bt<false><<<gproj, 512, 0, stream>>>(Xq, Xk, Xv,
                                            Wqb, Wkb, Wvb,
                                            bq, bk, bv,
                                            (void*)Qp, (void*)Kp, (void*)Vt,
                                            NB * NS, ND, ND, 2, QSCL);

  attn_fwd<<<dim3(512, 1, 1), 512, 0, stream>>>(Qp, Kp, Vt, (const uint2*)Mb, Xa);

  dim3 gout(ND / 128, (NB * NS) / 128, 1);
  gemm_bt<true><<<gout, 512, 0, stream>>>(Xa, Xa, Xa,
                                          Wob, Wob, Wob,
                                          bo, bo, bo,
                                          (void*)out, (void*)out, (void*)out,
                                          NB * NS, ND, ND, -1, 1.0f);
}

// Round 19
// 131.496 us; speedup vs baseline: 1.0570x; 1.0292x over previous
//
#include <hip/hip_runtime.h>
#include <hip/hip_bf16.h>
#include <cstdint>
#include <cstddef>

#define NB 2
#define NS 2048
#define ND 1024
#define NH 16
#define NDK 64
#define NT (NS / 64)

typedef __attribute__((ext_vector_type(4))) float f32x4;
typedef __attribute__((ext_vector_type(8))) short bf16x8;

#define MFMA_16x16x32_BF16(a,b,c) __builtin_amdgcn_mfma_f32_16x16x32_bf16((a),(b),(c),0,0,0)

__device__ __forceinline__ uint16_t f2bf(float f){
  uint32_t u = __float_as_uint(f);
  u += 0x7fffu + ((u >> 16) & 1u);   // round-to-nearest-even
  return (uint16_t)(u >> 16);
}
__device__ __forceinline__ uint32_t bfpack2(float a, float b){
  uint32_t r;
  asm volatile("v_cvt_pk_bf16_f32 %0, %1, %2" : "=v"(r) : "v"(a), "v"(b));
  return r;
}
// raw HW exp2 (safe: inputs bounded, no denormal path needed; masked after)
__device__ __forceinline__ float fexp2(float x){
  float r;
  asm volatile("v_exp_f32 %0, %1" : "=v"(r) : "v"(x));
  return r;
}
__device__ __forceinline__ void gload_lds16(const void* g, void* l){
  __builtin_amdgcn_global_load_lds((const __attribute__((address_space(1))) void*)g,
                                   (__attribute__((address_space(3))) void*)l, 16, 0, 0);
}

// ------- fused prep: y=0..2 act cvt, y=3 mask->bits, y=4..7 weight cvt ------
__global__ void prep_all(const float* __restrict__ q, const float* __restrict__ k,
                         const float* __restrict__ v,
                         const float* __restrict__ wq, const float* __restrict__ wk,
                         const float* __restrict__ wv, const float* __restrict__ wo,
                         uint16_t* __restrict__ oq, uint16_t* __restrict__ ok,
                         uint16_t* __restrict__ ov,
                         uint16_t* __restrict__ owq, uint16_t* __restrict__ owk,
                         uint16_t* __restrict__ owv, uint16_t* __restrict__ owo,
                         const int* __restrict__ mask, unsigned long long* __restrict__ bits,
                         int n8a, int n8w, int nchunks){
  const int y = blockIdx.y;
  if(y == 3){
    int wid  = (blockIdx.x * blockDim.x + threadIdx.x) >> 6;
    int lane = threadIdx.x & 63;
    int nw   = (gridDim.x * blockDim.x) >> 6;
    for(int ch = wid; ch < nchunks; ch += nw){
      int mv = mask[(size_t)ch * 64 + lane];
      unsigned long long bb = __ballot(mv != 0);
      if(lane == 0) bits[ch] = bb;
    }
    return;
  }
  const float* in; uint16_t* out; int n8;
  switch(y){
    case 0: in = q;  out = oq;  n8 = n8a; break;
    case 1: in = k;  out = ok;  n8 = n8a; break;
    case 2: in = v;  out = ov;  n8 = n8a; break;
    case 4: in = wq; out = owq; n8 = n8w; break;
    case 5: in = wk; out = owk; n8 = n8w; break;
    case 6: in = wv; out = owv; n8 = n8w; break;
    default: in = wo; out = owo; n8 = n8w; break;
  }
  int i0 = blockIdx.x * blockDim.x + threadIdx.x;
  int stride = gridDim.x * blockDim.x;
  for(int i = i0; i < n8; i += stride){
    const float4* p = (const float4*)(in) + (size_t)i * 2;
    float4 x = p[0], yv = p[1];
    bf16x8 o;
    o[0]=(short)f2bf(x.x);  o[1]=(short)f2bf(x.y);  o[2]=(short)f2bf(x.z);  o[3]=(short)f2bf(x.w);
    o[4]=(short)f2bf(yv.x); o[5]=(short)f2bf(yv.y); o[6]=(short)f2bf(yv.z); o[7]=(short)f2bf(yv.w);
    *((bf16x8*)(out) + i) = o;
  }
}

// ---------------- GEMM: 512 threads / 8 waves, 128x128 tile, BK=64 ----------
// XCD-aware 1-D grid: lin = blockIdx.x; xcd = lin&7 owns output rows
// y in {xcd*4 .. xcd*4+3} (A panels 1MB, L2-resident per XCD), all x, all z.
// idx>>5 = z (proj grid 768: z 0..2; out grid 256: z = 0 always).
// qscale: epilogue scale for z==0; vtz: transposed per-head Vt output.
template<bool OUTF32>
__global__ __launch_bounds__(512, 4)
void gemm_bt(const uint16_t* __restrict__ A0, const uint16_t* __restrict__ A1, const uint16_t* __restrict__ A2,
             const uint16_t* __restrict__ W0, const uint16_t* __restrict__ W1, const uint16_t* __restrict__ W2,
             const float* __restrict__ b0, const float* __restrict__ b1, const float* __restrict__ b2,
             void* __restrict__ C0, void* __restrict__ C1, void* __restrict__ C2,
             int M, int N, int K, int vtz, float qscale)
{
  const int lin = blockIdx.x;
  const int xcd = lin & 7, idx = lin >> 3;
  const int z   = idx >> 5;                 // 32 blocks per (xcd, z)
  const int r   = idx & 31;
  const int by  = xcd * 4 + (r >> 3);       // y 0..31
  const int bx  = r & 7;                    // x 0..7

  const uint16_t* A   = (z == 0) ? A0 : (z == 1) ? A1 : A2;
  const uint16_t* W   = (z == 0) ? W0 : (z == 1) ? W1 : W2;
  const float*   bias = (z == 0) ? b0 : (z == 1) ? b1 : b2;
  void*          Cout = (z == 0) ? C0 : (z == 1) ? C1 : C2;
  const float    csc  = (z == 0) ? qscale : 1.0f;

  __shared__ __align__(16) uint16_t Asm[128 * 64];
  __shared__ __align__(16) uint16_t Bsm[128 * 64];

  const int t = threadIdx.x;
  const int lane = t & 63, w = t >> 6;          // w = 0..7
  const int l15 = lane & 15, g = lane >> 4;
  const int bm = by * 128, bn = bx * 128;
  const int wr = (w >> 2) * 64, wc = (w & 3) * 32;

  f32x4 acc[4][2] = {};

  const int srow = lane >> 3;
  const int schk = (lane & 7) ^ srow;

  const uint16_t* gA = A + (size_t)(bm + w * 16 + srow) * K + schk * 8;
  const uint16_t* gB = W + (size_t)(bn + w * 16 + srow) * K + schk * 8;
  uint16_t* lA = &Asm[(w * 16) * 64];
  uint16_t* lB = &Bsm[(w * 16) * 64];

  const int xr = l15 & 7;
  int aOff[2][4], bOff[2][2];
  #pragma unroll
  for(int kk = 0; kk < 2; ++kk){
    #pragma unroll
    for(int m = 0; m < 4; ++m)
      aOff[kk][m] = (wr + m*16 + l15) * 64 + (((kk*4 + g) ^ xr) << 3);
    #pragma unroll
    for(int n = 0; n < 2; ++n)
      bOff[kk][n] = (wc + n*16 + l15) * 64 + (((kk*4 + g) ^ xr) << 3);
  }

  for(int k0 = 0; k0 < K; k0 += 64){
    #pragma unroll
    for(int j = 0; j < 2; ++j){
      gload_lds16(gA + (size_t)(8 * j) * K, lA + (8 * j) * 64);
      gload_lds16(gB + (size_t)(8 * j) * K, lB + (8 * j) * 64);
    }
    gA += 64; gB += 64;
    __syncthreads();
    #pragma unroll
    for(int kk = 0; kk < 2; ++kk){
      bf16x8 af[4], bfr[2];
      #pragma unroll
      for(int m = 0; m < 4; ++m) af[m]  = *(const bf16x8*)&Asm[aOff[kk][m]];
      #pragma unroll
      for(int n = 0; n < 2; ++n) bfr[n] = *(const bf16x8*)&Bsm[bOff[kk][n]];
      #pragma unroll
      for(int m = 0; m < 4; ++m)
        #pragma unroll
        for(int n = 0; n < 2; ++n)
          acc[m][n] = MFMA_16x16x32_BF16(af[m], bfr[n], acc[m][n]);
    }
    __syncthreads();
  }

  if(z == vtz){
    uint16_t* Vt = (uint16_t*)Cout;
    #pragma unroll
    for(int m = 0; m < 4; ++m){
      const int row = bm + wr + m*16 + g*4;
      const int bb = row >> 11, ss = row & (NS - 1);
      #pragma unroll
      for(int n = 0; n < 2; ++n){
        const int col = bn + wc + n*16 + l15;
        const float bv = bias[col];
        float v0 = acc[m][n][0] + bv, v1 = acc[m][n][1] + bv;
        float v2 = acc[m][n][2] + bv, v3 = acc[m][n][3] + bv;
        uint2 pk; pk.x = bfpack2(v0, v1); pk.y = bfpack2(v2, v3);
        size_t dst = ((size_t)(bb * NH + (col >> 6)) * NDK + (col & 63)) * NS + ss;
        *(uint2*)&Vt[dst] = pk;
      }
    }
  } else {
    #pragma unroll
    for(int m = 0; m < 4; ++m){
      const int row = bm + wr + m*16 + g*4;
      #pragma unroll
      for(int n = 0; n < 2; ++n){
        const int col = bn + wc + n*16 + l15;
        const float bv = bias[col];
        #pragma unroll
        for(int j = 0; j < 4; ++j){
          float v = (acc[m][n][j] + bv) * csc;
          if (OUTF32) ((float*)Cout)[(size_t)(row + j) * N + col] = v;
          else        ((uint16_t*)Cout)[(size_t)(row + j) * N + col] = f2bf(v);
        }
      }
    }
  }
}

// ---------------- Flash attention: QBLK=128, 8 waves, 2 kv-tiles/barrier ----
// XCD-aware 1-D grid (512 blocks): xcd = lin&7 owns head-batches 4*xcd..+3.
// 4-buffer LDS (2 pairs), 6 vmem/pair, vmcnt(6) counted wait, raw exp2,
// bfe mask, ones-MFMA denominator, Q pre-scaled.
__device__ __forceinline__ int swz64(int r, int chunk){
  return r * 64 + (((chunk) ^ (r & 7)) << 3);
}

__global__ __launch_bounds__(512, 2)
void attn_fwd(const uint16_t* __restrict__ Qp, const uint16_t* __restrict__ Kp,
              const uint16_t* __restrict__ Vtg, const uint2* __restrict__ Mbits,
              uint16_t* __restrict__ Xo)
{
  __shared__ __align__(16) uint16_t Ksm[4][64 * 64];
  __shared__ __align__(16) uint16_t Vtsm[4][64 * 64];
  __shared__ __align__(16) uint16_t Psm[8][16 * 64];

  const int lin = blockIdx.x;
  const int xcd = lin & 7, idx = lin >> 3;
  const int hb  = xcd * 4 + (idx >> 4);       // head-batch 0..31
  const int b   = hb >> 4, h = hb & 15;
  const int q0  = (idx & 15) * 128;

  const int t = threadIdx.x, lane = t & 63, w = t >> 6;   // w = 0..7
  const int l15 = lane & 15, g = lane >> 4;
  const int qbase = q0 + w * 16;

  bf16x8 qf0, qf1;
  {
    const uint16_t* qptr = Qp + (size_t)(b * NS + qbase + l15) * ND + h * NDK + g * 8;
    qf0 = *(const bf16x8*)(qptr);
    qf1 = *(const bf16x8*)(qptr + 32);
  }

  bf16x8 ones;
  #pragma unroll
  for(int e = 0; e < 8; ++e) ones[e] = (short)0x3F80;   // bf16 1.0

  f32x4 acc[4] = {};
  f32x4 acl = {};

  const int srow = lane >> 3;              // 0..7
  const int schk = (lane & 7) ^ srow;      // XOR involution within 8-row group

  const uint16_t* gK0 = Kp + (size_t)(b * NS + w * 8 + srow) * ND + h * NDK + schk * 8;
  const uint16_t* gV0 = Vtg + (size_t)(b * NH + h) * NDK * NS + (size_t)(w * 8 + srow) * NS + schk * 8;

  uint16_t* lK = &Ksm[0][(w * 8) * 64];
  uint16_t* lV = &Vtsm[0][(w * 8) * 64];

  int kOffA[4], kOffB[4], vOff[2][4];
  #pragma unroll
  for(int i = 0; i < 4; ++i){
    kOffA[i] = swz64(i * 16 + l15, g);
    kOffB[i] = swz64(i * 16 + l15, g + 4);
  }
  #pragma unroll
  for(int c2 = 0; c2 < 2; ++c2)
    #pragma unroll
    for(int tt = 0; tt < 4; ++tt)
      vOff[c2][tt] = swz64(tt * 16 + l15, c2 * 4 + g);
  const int xorw = (l15 & 7) << 3;
  const int prow = l15 * 64;
  int pW[4], pR[2];
  #pragma unroll
  for(int i = 0; i < 4; ++i) pW[i] = prow + ((16 * i + g * 4) ^ xorw);
  #pragma unroll
  for(int c2 = 0; c2 < 2; ++c2) pR[c2] = prow + ((c2 * 32 + g * 8) ^ xorw);
  uint16_t* PsmW = Psm[w];

  const uint2* Mptr = Mbits + (size_t)(b * NS + qbase + l15) * (NS / 64);

  // prologue: stage tiles 0,1 into pair 0 (4 gloads + 2 mask loads = 6 vmem)
  gload_lds16(gK0,           lK);
  gload_lds16(gV0,           lV);
  gload_lds16(gK0 + 64 * ND, lK + 4096);
  gload_lds16(gV0 + 64,      lV + 4096);
  uint2 mm0 = Mptr[0], mm1 = Mptr[1];
  gK0 += 128 * ND; gV0 += 128;

  int p = 0;
  for(int it = 0; it < NT / 2; ++it){
    uint2 mn0, mn1;
    if(it + 1 < NT / 2){
      const int nc = (p ^ 1) * 8192;
      gload_lds16(gK0,           lK + nc);
      gload_lds16(gV0,           lV + nc);
      gload_lds16(gK0 + 64 * ND, lK + nc + 4096);
      gload_lds16(gV0 + 64,      lV + nc + 4096);
      mn0 = Mptr[2 * it + 2];
      mn1 = Mptr[2 * it + 3];
      gK0 += 128 * ND; gV0 += 128;
      asm volatile("s_waitcnt vmcnt(6)" ::: "memory");   // this pair's 6 landed
    } else {
      asm volatile("s_waitcnt vmcnt(0)" ::: "memory");
    }
    __builtin_amdgcn_s_barrier();

    #pragma unroll
    for(int half = 0; half < 2; ++half){
      const uint16_t* Kc = &Ksm[0][p * 8192 + half * 4096];
      const uint16_t* Vc = &Vtsm[0][p * 8192 + half * 4096];
      const uint2 mm = half ? mm1 : mm0;

      // QK^T swapped: s4[i] row=kv(16i+g*4+j), col=q(l15); Q pre-scaled
      f32x4 s4[4];
      __builtin_amdgcn_s_setprio(1);
      #pragma unroll
      for(int i = 0; i < 4; ++i){
        bf16x8 kf0 = *(const bf16x8*)&Kc[kOffA[i]];
        bf16x8 kf1 = *(const bf16x8*)&Kc[kOffB[i]];
        f32x4 zr = {};
        zr = MFMA_16x16x32_BF16(kf0, qf0, zr);
        zr = MFMA_16x16x32_BF16(kf1, qf1, zr);
        s4[i] = zr;
      }
      __builtin_amdgcn_s_setprio(0);

      // p = exp2(s) [raw v_exp_f32]; mask via 1-op v_bfe_i32 bit sign-extend
      const uint32_t w0 = mm.x >> (g * 4);
      const uint32_t w1 = mm.y >> (g * 4);
      #pragma unroll
      for(int i = 0; i < 4; ++i){
        const uint32_t ww = (i < 2) ? w0 : w1;
        float e0 = fexp2(s4[i][0]);
        float e1 = fexp2(s4[i][1]);
        float e2 = fexp2(s4[i][2]);
        float e3 = fexp2(s4[i][3]);
        int m0, m1, m2, m3;
        if((i & 1) == 0){
          asm("v_bfe_i32 %0, %1, 0, 1" : "=v"(m0) : "v"(ww));
          asm("v_bfe_i32 %0, %1, 1, 1" : "=v"(m1) : "v"(ww));
          asm("v_bfe_i32 %0, %1, 2, 1" : "=v"(m2) : "v"(ww));
          asm("v_bfe_i32 %0, %1, 3, 1" : "=v"(m3) : "v"(ww));
        } else {
          asm("v_bfe_i32 %0, %1, 16, 1" : "=v"(m0) : "v"(ww));
          asm("v_bfe_i32 %0, %1, 17, 1" : "=v"(m1) : "v"(ww));
          asm("v_bfe_i32 %0, %1, 18, 1" : "=v"(m2) : "v"(ww));
          asm("v_bfe_i32 %0, %1, 19, 1" : "=v"(m3) : "v"(ww));
        }
        s4[i][0] = __uint_as_float((uint32_t)m0 & __float_as_uint(e0));
        s4[i][1] = __uint_as_float((uint32_t)m1 & __float_as_uint(e1));
        s4[i][2] = __uint_as_float((uint32_t)m2 & __float_as_uint(e2));
        s4[i][3] = __uint_as_float((uint32_t)m3 & __float_as_uint(e3));
      }

      // pack P -> per-wave LDS (b64 writes)
      #pragma unroll
      for(int i = 0; i < 4; ++i){
        uint2 pk;
        pk.x = bfpack2(s4[i][0], s4[i][1]);
        pk.y = bfpack2(s4[i][2], s4[i][3]);
        *(uint2*)&PsmW[pW[i]] = pk;
      }

      // PV (+ denominator via ones-column MFMA)
      __builtin_amdgcn_s_setprio(1);
      #pragma unroll
      for(int c2 = 0; c2 < 2; ++c2){
        bf16x8 pf = *(const bf16x8*)&PsmW[pR[c2]];
        acl = MFMA_16x16x32_BF16(pf, ones, acl);
        #pragma unroll
        for(int tt = 0; tt < 4; ++tt){
          bf16x8 vf = *(const bf16x8*)&Vc[vOff[c2][tt]];
          acc[tt] = MFMA_16x16x32_BF16(pf, vf, acc[tt]);
        }
      }
      __builtin_amdgcn_s_setprio(0);
    }

    asm volatile("s_waitcnt lgkmcnt(0)" ::: "memory");
    __builtin_amdgcn_s_barrier();
    p ^= 1;
    mm0 = mn0; mm1 = mn1;
  }

  // finalize: l already in output-row layout (row = g*4+j)
  #pragma unroll
  for(int j = 0; j < 4; ++j){
    const float inv = 1.0f / acl[j];
    const int qr = qbase + g * 4 + j;
    #pragma unroll
    for(int tt = 0; tt < 4; ++tt)
      Xo[(size_t)(b * NS + qr) * ND + h * NDK + tt * 16 + l15] = f2bf(acc[tt][j] * inv);
  }
}

// ---------------- host launch ------------------------------------------------
extern "C" void kernel_launch(void* const* d_in, const int* in_sizes, int n_in,
                              void* d_out, int out_size, void* d_ws, size_t ws_size,
                              hipStream_t stream)
{
  const float* query = (const float*)d_in[0];
  const float* key   = (const float*)d_in[1];
  const float* value = (const float*)d_in[2];
  const int*   mask  = (const int*)d_in[3];
  const float* Wq = (const float*)d_in[4];
  const float* bq = (const float*)d_in[5];
  const float* Wk = (const float*)d_in[6];
  const float* bk = (const float*)d_in[7];
  const float* Wv = (const float*)d_in[8];
  const float* bv = (const float*)d_in[9];
  const float* Wo = (const float*)d_in[10];
  const float* bo = (const float*)d_in[11];
  float* out = (float*)d_out;

  const size_t NX = (size_t)NB * NS * ND;   // 4,194,304
  const size_t NW = (size_t)ND * ND;        // 1,048,576

  uint16_t* ws  = (uint16_t*)d_ws;
  uint16_t* Xq  = ws;            // bf16 activations
  uint16_t* Xk  = Xq  + NX;
  uint16_t* Xv  = Xk  + NX;
  uint16_t* Wqb = Xv  + NX;
  uint16_t* Wkb = Wqb + NW;
  uint16_t* Wvb = Wkb + NW;
  uint16_t* Wob = Wvb + NW;
  uint16_t* Qp  = Wob + NW;
  uint16_t* Kp  = Qp  + NX;
  uint16_t* Vt  = Kp  + NX;      // V^T written directly by proj epilogue (z==2)
  uint16_t* Xa  = Vt  + NX;
  unsigned long long* Mb = (unsigned long long*)(Xa + NX);   // 1MB, own slot

  const int nchunks = (int)((size_t)NB * NS * NS / 64);   // 131072
  const float QSCL = 0.125f * 1.44269504f;   // log2(e)/sqrt(DK)

  prep_all<<<dim3(1024, 8), 256, 0, stream>>>(query, key, value, Wq, Wk, Wv, Wo,
                                              Xq, Xk, Xv, Wqb, Wkb, Wvb, Wob,
                                              mask, Mb, (int)(NX / 8), (int)(NW / 8), nchunks);

  gemm_bt<false><<<dim3(768), 512, 0, stream>>>(Xq, Xk, Xv,
                                                Wqb, Wkb, Wvb,
                                                bq, bk, bv,
                                                (void*)Qp, (void*)Kp, (void*)Vt,
                                                NB * NS, ND, ND, 2, QSCL);

  attn_fwd<<<dim3(512), 512, 0, stream>>>(Qp, Kp, Vt, (const uint2*)Mb, Xa);

  gemm_bt<true><<<dim3(256), 512, 0, stream>>>(Xa, Xa, Xa,
                                               Wob, Wob, Wob,
                                               bo, bo, bo,
                                               (void*)out, (void*)out, (void*)out,
                                               NB * NS, ND, ND, -1, 1.0f);
}